// Round 18
// baseline (562.141 us; speedup 1.0000x reference)
//
#include <hip/hip_runtime.h>
#include <stdint.h>

#define B_ 32
#define C_ 512
#define HW_ 4096
#define N_ 131072
#define K_ 512
#define QELEMS 67108864   /* B*C*H*W = 2^26 */
#define MARGIN 1e-3f
#define CAND   2.5e-3f
#define MAXC   16
#define RFCAP 131072      /* == N_: refine list can never overflow */

typedef __attribute__((ext_vector_type(8)))  short bf16x8;
typedef __attribute__((ext_vector_type(16))) float f32x16;

__device__ __forceinline__ ushort f2bf(float f) {   // RNE f32->bf16 (no NaN inputs)
  uint u = __float_as_uint(f);
  return (ushort)((u + 0x7FFFu + ((u >> 16) & 1u)) >> 16);
}

// ---------------------------------------------------------------------------
// numpy float32 pairwise sum of 512 floats (AVX512 base case, 8 vec accs,
// GCC _mm512_reduce_add_ps horizontal tree).
// ---------------------------------------------------------------------------
__device__ __forceinline__ float np_pw512(const float* a) {
  float P[4];
#pragma unroll
  for (int m = 0; m < 4; ++m) {
    const float* q = a + m * 128;
    float rv[16];
#pragma unroll
    for (int l = 0; l < 16; ++l) {
      float v0 = q[l],      v1 = q[16 + l],  v2 = q[32 + l],  v3 = q[48 + l];
      float v4 = q[64 + l], v5 = q[80 + l],  v6 = q[96 + l],  v7 = q[112 + l];
      rv[l] = ((v0 + v1) + (v2 + v3)) + ((v4 + v5) + (v6 + v7));
    }
    float u[8], w[4];
#pragma unroll
    for (int l = 0; l < 8; ++l) u[l] = rv[8 + l] + rv[l];
#pragma unroll
    for (int l = 0; l < 4; ++l) w[l] = u[4 + l] + u[l];
    P[m] = (w[0] + w[2]) + (w[1] + w[3]);
  }
  return (P[0] + P[1]) + (P[2] + P[3]);
}

// Same tree over squared elements (sq computed with __fmul_rn, as np does).
__device__ __forceinline__ float np_pw512_sq(const float* a) {
  float P[4];
#pragma unroll
  for (int m = 0; m < 4; ++m) {
    const float* q = a + m * 128;
    float rv[16];
#pragma unroll
    for (int l = 0; l < 16; ++l) {
      float v0 = __fmul_rn(q[l], q[l]);
      float v1 = __fmul_rn(q[16 + l], q[16 + l]);
      float v2 = __fmul_rn(q[32 + l], q[32 + l]);
      float v3 = __fmul_rn(q[48 + l], q[48 + l]);
      float v4 = __fmul_rn(q[64 + l], q[64 + l]);
      float v5 = __fmul_rn(q[80 + l], q[80 + l]);
      float v6 = __fmul_rn(q[96 + l], q[96 + l]);
      float v7 = __fmul_rn(q[112 + l], q[112 + l]);
      rv[l] = ((v0 + v1) + (v2 + v3)) + ((v4 + v5) + (v6 + v7));
    }
    float u[8], w[4];
#pragma unroll
    for (int l = 0; l < 8; ++l) u[l] = rv[8 + l] + rv[l];
#pragma unroll
    for (int l = 0; l < 4; ++l) w[l] = u[4 + l] + u[l];
    P[m] = (w[0] + w[2]) + (w[1] + w[3]);
  }
  return (P[0] + P[1]) + (P[2] + P[3]);
}

// ---------------------------------------------------------------------------
// K0: senp[k]; eT[c][k]; zero rcnt/ocnt and candCnt[N].
// ---------------------------------------------------------------------------
__global__ __launch_bounds__(256) void k_prep(const float* __restrict__ embed,
    float* __restrict__ senp, float* __restrict__ eT, int* __restrict__ rcnt,
    int* __restrict__ ocnt, int* __restrict__ candCnt)
{
  __shared__ float sqa[C_];
  int k = blockIdx.x;
  candCnt[blockIdx.x * 256 + threadIdx.x] = 0;   // 512*256 == N_
  for (int c = threadIdx.x; c < C_; c += 256) {
    float e = embed[k * C_ + c];
    eT[c * K_ + k] = e;
    sqa[c] = __fmul_rn(e, e);
  }
  __syncthreads();
  if (threadIdx.x == 0) {
    senp[k] = np_pw512(sqa);
    if (blockIdx.x == 0) { *rcnt = 0; *ocnt = 0; }
  }
}

// ---------------------------------------------------------------------------
// K0a: pack embed -> efrag fragment-major (unchanged, verified).
// ---------------------------------------------------------------------------
__global__ __launch_bounds__(256) void k_epack(const float* __restrict__ embed,
    ushort* __restrict__ efrag)
{
  const int cb = blockIdx.x;
  const int t = threadIdx.x;
  const int lane = t & 63, ksq = t >> 6;
  const int l31 = lane & 31, lhi = lane >> 5;
  const float* ep = embed + ((size_t)(cb * 32 + l31) << 9) + lhi * 8;
#pragma unroll
  for (int i = 0; i < 8; ++i) {
    int ks = ksq * 8 + i;
    float4 v0 = *(const float4*)(ep + ks * 16);
    float4 v1 = *(const float4*)(ep + ks * 16 + 4);
    uint u0 = (uint)f2bf(v0.x) | ((uint)f2bf(v0.y) << 16);
    uint u1 = (uint)f2bf(v0.z) | ((uint)f2bf(v0.w) << 16);
    uint u2 = (uint)f2bf(v1.x) | ((uint)f2bf(v1.y) << 16);
    uint u3 = (uint)f2bf(v1.z) | ((uint)f2bf(v1.w) << 16);
    ushort* op = efrag + (((size_t)(cb * 32 + ks)) * 64 + lane) * 8;
    *(uint4*)op = make_uint4(u0, u1, u2, u3);
  }
}

// ---------------------------------------------------------------------------
// K0b: x -> xfrag (bf16 fragment-major) + optional xT [b][hw][c] f32.
//      Unchanged, verified.
// ---------------------------------------------------------------------------
__global__ __launch_bounds__(256) void k_xsplit(const float* __restrict__ x,
    ushort* __restrict__ xfrag, float* __restrict__ xT)
{
  __shared__ float tile[64][66];
  const int bid = blockIdx.x;
  const int ht = bid & 63, ct = (bid >> 6) & 7, b = bid >> 9;
  const int t = threadIdx.x;
  const int r = t & 63, cq = t >> 6;
  const float* xp = x + (((size_t)(b * C_ + ct * 64)) << 12) + ht * 64 + r;
#pragma unroll
  for (int i = 0; i < 16; ++i) {
    int c = cq * 16 + i;
    tile[r][c] = xp[(size_t)c << 12];
  }
  __syncthreads();
  const int lane = t & 63, ksl = t >> 6;
  const int l31 = lane & 31, lhi = lane >> 5;
  const int ks = ct * 4 + ksl;
  const int cc = ksl * 16 + lhi * 8;
#pragma unroll
  for (int rbl = 0; rbl < 2; ++rbl) {
    int rr = rbl * 32 + l31;
    uint u[4];
#pragma unroll
    for (int j = 0; j < 4; ++j) {
      float f0 = tile[rr][cc + 2 * j];
      float f1 = tile[rr][cc + 2 * j + 1];
      u[j] = (uint)f2bf(f0) | ((uint)f2bf(f1) << 16);
    }
    size_t rb = (size_t)b * 128 + ht * 2 + rbl;
    ushort* op = xfrag + ((rb * 32 + ks) * 64 + lane) * 8;
    *(uint4*)op = make_uint4(u[0], u[1], u[2], u[3]);
  }
  if (xT) {
    const int r2 = t >> 2, cs2 = (t & 3) << 4;
    float* op = xT + ((size_t)(b * HW_ + ht * 64 + r2) << 9) + ct * 64 + cs2;
#pragma unroll
    for (int j = 0; j < 4; ++j) {
      float4 v;
      v.x = tile[r2][cs2 + 4 * j + 0];
      v.y = tile[r2][cs2 + 4 * j + 1];
      v.z = tile[r2][cs2 + 4 * j + 2];
      v.w = tile[r2][cs2 + 4 * j + 3];
      *(float4*)(op + 4 * j) = v;
    }
  }
}

// ---------------------------------------------------------------------------
// K1: MFMA argmin — round-17 structure (4 chains, direct frag-major loads,
//     4 waves/SIMD) with per-lane TOP-3 tracking: append lane top-2 within
//     thr as candidates; route to full fallback only if lane-THIRD <= thr
//     (provably complete, and same-lane top-2 pairs no longer hit fallback).
// ---------------------------------------------------------------------------
__global__ __launch_bounds__(512, 4) void k_argmin(const ushort* __restrict__ xfrag,
    const ushort* __restrict__ efrag, const float* __restrict__ senp,
    int* __restrict__ idx_out, int* __restrict__ rcnt, int* __restrict__ rrows,
    int* __restrict__ candCnt, int* __restrict__ cand)
{
  __shared__ float ses[K_];
  __shared__ float mbL[64][4], msL[64][4];
  __shared__ int   miL[64][4];
  __shared__ float rowBest[64];
  __shared__ int   rowFlag[64];
  const int t = threadIdx.x;
  const int lane = t & 63, wid = t >> 6;
  const int wc = wid & 3, wr = wid >> 2;
  const int l31 = lane & 31, lhi = lane >> 5;
  const int b = blockIdx.x >> 6;
  const int rowt = blockIdx.x & 63;

  for (int i = t; i < K_; i += 512) ses[i] = senp[i];
  __syncthreads();

  const size_t rb = (size_t)b * 128 + rowt * 2 + wr;
  const bf16x8* xq  = (const bf16x8*)xfrag + rb * 2048 + lane;
  const bf16x8* eq0 = (const bf16x8*)efrag + (size_t)(wc * 4 + 0) * 2048 + lane;
  const bf16x8* eq1 = (const bf16x8*)efrag + (size_t)(wc * 4 + 1) * 2048 + lane;
  const bf16x8* eq2 = (const bf16x8*)efrag + (size_t)(wc * 4 + 2) * 2048 + lane;
  const bf16x8* eq3 = (const bf16x8*)efrag + (size_t)(wc * 4 + 3) * 2048 + lane;

  f32x16 a0 = {0,0,0,0,0,0,0,0,0,0,0,0,0,0,0,0};
  f32x16 a1 = a0, a2 = a0, a3 = a0;
  __builtin_amdgcn_s_setprio(1);
#pragma unroll 8
  for (int ks = 0; ks < 32; ++ks) {
    bf16x8 xf = xq[ks * 64];
    a0 = __builtin_amdgcn_mfma_f32_32x32x16_bf16(eq0[ks * 64], xf, a0, 0, 0, 0);
    a1 = __builtin_amdgcn_mfma_f32_32x32x16_bf16(eq1[ks * 64], xf, a1, 0, 0, 0);
    a2 = __builtin_amdgcn_mfma_f32_32x32x16_bf16(eq2[ks * 64], xf, a2, 0, 0, 0);
    a3 = __builtin_amdgcn_mfma_f32_32x32x16_bf16(eq3[ks * 64], xf, a3, 0, 0, 0);
  }
  __builtin_amdgcn_s_setprio(0);

  // per-lane top-3 (values) with indices for top-2
  float best = 1e30f, second = 1e30f, third = 1e30f;
  int bidx = 0, sidx = 0;
#pragma unroll
  for (int r = 0; r < 16; ++r) {
    int crow = (r & 3) + 8 * (r >> 2) + 4 * lhi;
    float v; int code;
#define TOP3_UPD                                                             \
    if (v < best || (v == best && code < bidx)) {                            \
      third = second; second = best; sidx = bidx; best = v; bidx = code;     \
    } else if (v < second) { third = second; second = v; sidx = code; }      \
    else if (v < third) { third = v; }
    code = wc * 128 + 0  + crow; v = ses[code] - 2.0f * a0[r]; TOP3_UPD
    code = wc * 128 + 32 + crow; v = ses[code] - 2.0f * a1[r]; TOP3_UPD
    code = wc * 128 + 64 + crow; v = ses[code] - 2.0f * a2[r]; TOP3_UPD
    code = wc * 128 + 96 + crow; v = ses[code] - 2.0f * a3[r]; TOP3_UPD
#undef TOP3_UPD
  }
  // pre-merge copies for candidate collection
  const float pb = best, ps = second, pth = third;
  const int   pi = bidx, psi = sidx;
  // cross-half-wave merge (lanes l and l+32 share a row) on top-2
  {
    float ob = __shfl_xor(best, 32, 64);
    float os = __shfl_xor(second, 32, 64);
    int   oi = __shfl_xor(bidx, 32, 64);
    float ns = fminf(fmaxf(best, ob), fminf(second, os));
    if (ob < best || (ob == best && oi < bidx)) { best = ob; bidx = oi; }
    second = ns;
  }
  if (lane < 32) {
    int rr = wr * 32 + l31;
    mbL[rr][wc] = best; msL[rr][wc] = second; miL[rr][wc] = bidx;
  }
  __syncthreads();
  if (t < 64) {
    float Bv = 1e30f, Sv = 1e30f; int Iv = 0;
#pragma unroll
    for (int q = 0; q < 4; ++q) {
      float b1 = mbL[t][q], s1 = msL[t][q]; int i1 = miL[t][q];
      if (b1 < Bv || (b1 == Bv && i1 < Iv)) { Sv = fminf(Bv, s1); Bv = b1; Iv = i1; }
      else Sv = fminf(Sv, b1);
    }
    int n = b * HW_ + rowt * 64 + t;
    idx_out[n] = Iv;
    rowBest[t] = Bv;
    int fl = (Sv - Bv < MARGIN) ? 1 : 0;
    rowFlag[t] = fl;
    if (fl) {
      int p = atomicAdd(rcnt, 1);
      if (p < RFCAP) rrows[p] = n;
    }
  }
  __syncthreads();
  // candidate collection: lane top-2 appended; lane-third within thr -> route
  {
    const int rr = wr * 32 + l31;
    if (rowFlag[rr]) {
      const float thr = rowBest[rr] + CAND;
      const int n = b * HW_ + rowt * 64 + rr;
      if (pb <= thr) {
        int p = atomicAdd(&candCnt[n], 1);
        if (p < MAXC) cand[(size_t)n * MAXC + p] = pi;
      }
      if (ps <= thr) {
        int p = atomicAdd(&candCnt[n], 1);
        if (p < MAXC) cand[(size_t)n * MAXC + p] = psi;
      }
      if (pth <= thr) {
        // >=3 candidates in this lane (rare): route row to full fallback
        atomicAdd(&candCnt[n], 64);
      }
    }
  }
}

// ---------------------------------------------------------------------------
// K2: candidate refine. 4 rows/block (wave per row); lane = candidate.
//     Overflow rows (candCnt > MAXC) -> olist -> full fallback.
// ---------------------------------------------------------------------------
__global__ __launch_bounds__(256) void k_refine(const float* __restrict__ x,
    const float* __restrict__ xT, const float* __restrict__ embed,
    const float* __restrict__ senp,
    const int* __restrict__ rcnt, const int* __restrict__ rrows,
    const int* __restrict__ candCnt, const int* __restrict__ cand,
    int* __restrict__ ocnt, int* __restrict__ olist,
    int* __restrict__ idx_out)
{
  __shared__ float xls[4][516];
  __shared__ float SxSh[4];
  __shared__ int   nrow[4];
  const int t = threadIdx.x;
  const int lane = t & 63, w = t >> 6;
  int cnt = *rcnt; if (cnt > RFCAP) cnt = RFCAP;
  for (int base = blockIdx.x * 4; base < cnt; base += gridDim.x * 4) {
    __syncthreads();
    if (t < 4) {
      int i = base + t;
      nrow[t] = rrows[i < cnt ? i : base];
    }
    __syncthreads();
    if (xT) {
      for (int i = t; i < 4 * C_; i += 256) {
        int s = i >> 9, c = i & 511;
        xls[s][c] = xT[((size_t)nrow[s] << 9) + c];
      }
    } else {
      for (int i = t; i < 4 * C_; i += 256) {
        int s = i >> 9, c = i & 511;
        int n = nrow[s];
        int b = n >> 12, hw = n & 4095;
        xls[s][c] = x[(((size_t)(b * C_ + c)) << 12) + hw];
      }
    }
    __syncthreads();
    if (t < 4) SxSh[t] = np_pw512_sq(&xls[t][0]);
    __syncthreads();
    const int n = nrow[w];
    const int cc = candCnt[n];
    float d = 1e30f; int code = 0x7fffffff;
    if (cc <= MAXC) {
      if (lane < cc) {
        code = cand[(size_t)n * MAXC + lane];
        const float* e = embed + (size_t)code * C_;
        const float* xr = &xls[w][0];
        float s1 = 0.f, s2 = 0.f;
        for (int c = 0; c < 384; ++c)  s1 = fmaf(xr[c], e[c], s1);
        for (int c = 384; c < 512; ++c) s2 = fmaf(xr[c], e[c], s2);
        float M = s1 + s2;
        d = (SxSh[w] + senp[code]) - 2.0f * M;
      }
#pragma unroll
      for (int off = 1; off < 16; off <<= 1) {
        float ov = __shfl_xor(d, off, 64);
        int   oc = __shfl_xor(code, off, 64);
        if (ov < d || (ov == d && oc < code)) { d = ov; code = oc; }
      }
      if (lane == 0 && base + w < cnt) idx_out[n] = code;
    } else {
      if (lane == 0 && base + w < cnt) {
        int p = atomicAdd(ocnt, 1);
        if (p < RFCAP) olist[p] = n;
      }
    }
  }
}

// ---------------------------------------------------------------------------
// K2b: full 512-code np-replica re-rank — fallback for overflow rows.
// ---------------------------------------------------------------------------
__global__ __launch_bounds__(512) void k_refine_full(const float* __restrict__ x,
    const float* __restrict__ xT, const float* __restrict__ eT,
    const float* __restrict__ senp,
    const int* __restrict__ rcnt, const int* __restrict__ rrows,
    int* __restrict__ idx_out)
{
  __shared__ float xls[8][520];
  __shared__ float SxSh[8];
  __shared__ int   nrow[8];
  __shared__ float wval[8][8];
  __shared__ int   widx[8][8];
  const int t = threadIdx.x;
  const int lane = t & 63, w = t >> 6;
  int cnt = *rcnt; if (cnt > RFCAP) cnt = RFCAP;
  for (int base = blockIdx.x * 8; base < cnt; base += gridDim.x * 8) {
    __syncthreads();
    if (t < 8) {
      int i = base + t;
      nrow[t] = rrows[i < cnt ? i : base];
    }
    __syncthreads();
    if (xT) {
#pragma unroll
      for (int rr = 0; rr < 8; ++rr)
        xls[rr][t] = xT[((size_t)nrow[rr] << 9) + t];
    } else {
#pragma unroll
      for (int rr = 0; rr < 8; ++rr) {
        int n = nrow[rr];
        int b = n >> 12, hw = n & 4095;
        xls[rr][t] = x[(((size_t)(b * C_ + t)) << 12) + hw];
      }
    }
    __syncthreads();
    if (t < 8) SxSh[t] = np_pw512_sq(&xls[t][0]);
    __syncthreads();
    const float* ep = eT + t;
    float a1[8], a2[8];
#pragma unroll
    for (int rr = 0; rr < 8; ++rr) { a1[rr] = 0.f; a2[rr] = 0.f; }
    for (int c4 = 0; c4 < 384; c4 += 4) {
      float e0 = ep[(size_t)(c4 + 0) << 9];
      float e1 = ep[(size_t)(c4 + 1) << 9];
      float e2 = ep[(size_t)(c4 + 2) << 9];
      float e3 = ep[(size_t)(c4 + 3) << 9];
#pragma unroll
      for (int rr = 0; rr < 8; ++rr) {
        float4 xv = *(const float4*)&xls[rr][c4];
        a1[rr] = fmaf(xv.x, e0, a1[rr]);
        a1[rr] = fmaf(xv.y, e1, a1[rr]);
        a1[rr] = fmaf(xv.z, e2, a1[rr]);
        a1[rr] = fmaf(xv.w, e3, a1[rr]);
      }
    }
    for (int c4 = 384; c4 < 512; c4 += 4) {
      float e0 = ep[(size_t)(c4 + 0) << 9];
      float e1 = ep[(size_t)(c4 + 1) << 9];
      float e2 = ep[(size_t)(c4 + 2) << 9];
      float e3 = ep[(size_t)(c4 + 3) << 9];
#pragma unroll
      for (int rr = 0; rr < 8; ++rr) {
        float4 xv = *(const float4*)&xls[rr][c4];
        a2[rr] = fmaf(xv.x, e0, a2[rr]);
        a2[rr] = fmaf(xv.y, e1, a2[rr]);
        a2[rr] = fmaf(xv.z, e2, a2[rr]);
        a2[rr] = fmaf(xv.w, e3, a2[rr]);
      }
    }
    float se = senp[t];
    float bv[8]; int bi[8];
#pragma unroll
    for (int rr = 0; rr < 8; ++rr) {
      float M = a1[rr] + a2[rr];
      bv[rr] = (SxSh[rr] + se) - 2.0f * M;
      bi[rr] = t;
    }
#pragma unroll
    for (int off = 1; off < 64; off <<= 1) {
#pragma unroll
      for (int rr = 0; rr < 8; ++rr) {
        float ov = __shfl_xor(bv[rr], off, 64);
        int   oi = __shfl_xor(bi[rr], off, 64);
        if (ov < bv[rr] || (ov == bv[rr] && oi < bi[rr])) { bv[rr] = ov; bi[rr] = oi; }
      }
    }
    if (lane == 0) {
#pragma unroll
      for (int rr = 0; rr < 8; ++rr) { wval[w][rr] = bv[rr]; widx[w][rr] = bi[rr]; }
    }
    __syncthreads();
    if (t < 8) {
      float Bv = wval[0][t]; int Iv = widx[0][t];
#pragma unroll
      for (int q = 1; q < 8; ++q) {
        float ov = wval[q][t]; int oi = widx[q][t];
        if (ov < Bv || (ov == Bv && oi < Iv)) { Bv = ov; Iv = oi; }
      }
      if (base + t < cnt) idx_out[nrow[t]] = Iv;
    }
  }
}

// ---------------------------------------------------------------------------
// K3: gather + loss (unchanged).
// ---------------------------------------------------------------------------
__global__ __launch_bounds__(256) void k_gather(const float* __restrict__ x,
    const float* __restrict__ embed, const int* __restrict__ idx,
    float* __restrict__ out_q, double* __restrict__ loss_part)
{
  __shared__ float ecol[32][512];
  const int bid = blockIdx.x;
  const int hch = bid & 1, cch = (bid >> 1) & 15, b = bid >> 5;
  const int c0 = cch * 32, hw0 = hch * 2048;
  const int t = threadIdx.x;
  for (int i = t; i < 512 * 32; i += 256) {
    int c = i & 31, k = i >> 5;
    ecol[c][(k + c0 + c) & 511] = embed[((size_t)k << 9) + c0 + c];
  }
  __syncthreads();
  int kreg[8];
#pragma unroll
  for (int j = 0; j < 8; ++j)
    kreg[j] = idx[(b << 12) + hw0 + t + 256 * j];
  double s = 0.0;
  for (int c = 0; c < 32; ++c) {
    const float* xrow = x + (((size_t)(b * C_ + c0 + c)) << 12) + hw0;
    float* orow = out_q + (((size_t)(b * C_ + c0 + c)) << 12) + hw0;
#pragma unroll
    for (int j = 0; j < 8; ++j) {
      float q  = ecol[c][(kreg[j] + c0 + c) & 511];
      float xv = xrow[t + 256 * j];
      orow[t + 256 * j] = q;
      double d = (double)q - (double)xv;
      s += d * d;
    }
  }
  for (int off = 32; off > 0; off >>= 1) s += __shfl_down(s, off, 64);
  __shared__ double wsum[4];
  if ((t & 63) == 0) wsum[t >> 6] = s;
  __syncthreads();
  if (t == 0)
    loss_part[bid] = (wsum[0] + wsum[1]) + (wsum[2] + wsum[3]);
}

// ---------------------------------------------------------------------------
// K4: per-batch unique-code count + write idx_b as float.
// ---------------------------------------------------------------------------
__global__ __launch_bounds__(256) void k_pplx(const int* __restrict__ idx,
    float* __restrict__ out_idxf, int* __restrict__ counts)
{
  __shared__ int flags[K_];
  __shared__ int red[256];
  int b = blockIdx.x;
  for (int i = threadIdx.x; i < K_; i += 256) flags[i] = 0;
  __syncthreads();
  for (int hw = threadIdx.x; hw < HW_; hw += 256) {
    int k = idx[(b << 12) + hw];
    flags[k] = 1;
    out_idxf[(b << 12) + hw] = (float)k;
  }
  __syncthreads();
  int c = 0;
  for (int i = threadIdx.x; i < K_; i += 256) c += flags[i];
  red[threadIdx.x] = c;
  __syncthreads();
  for (int st = 128; st > 0; st >>= 1) {
    if (threadIdx.x < st) red[threadIdx.x] += red[threadIdx.x + st];
    __syncthreads();
  }
  if (threadIdx.x == 0) counts[b] = red[0];
}

// ---------------------------------------------------------------------------
// K5: finalize scalars (1024 loss partials).
// ---------------------------------------------------------------------------
__global__ __launch_bounds__(256) void k_final(const double* __restrict__ loss_part,
    const int* __restrict__ counts, float* __restrict__ out_loss,
    float* __restrict__ out_pplx)
{
  __shared__ double sred[256];
  double s = 0.0;
  for (int i = threadIdx.x; i < 1024; i += 256) s += loss_part[i];
  sred[threadIdx.x] = s;
  __syncthreads();
  for (int st = 128; st > 0; st >>= 1) {
    if (threadIdx.x < st) sred[threadIdx.x] += sred[threadIdx.x + st];
    __syncthreads();
  }
  if (threadIdx.x == 0) {
    *out_loss = (float)(1.25 * sred[0] / (double)QELEMS);
    int c = 0;
    for (int i = 0; i < B_; ++i) c += counts[i];
    *out_pplx = (float)c / (float)B_;
  }
}

// ---------------------------------------------------------------------------
extern "C" void kernel_launch(void* const* d_in, const int* in_sizes, int n_in,
                              void* d_out, int out_size, void* d_ws, size_t ws_size,
                              hipStream_t stream)
{
  const float* x     = (const float*)d_in[0];
  const float* embed = (const float*)d_in[1];
  float* out      = (float*)d_out;
  float* out_loss = out;                  // [0]
  float* out_q    = out + 1;              // [1 .. 1+QELEMS)
  float* out_pplx = out + 1 + QELEMS;     // [1+QELEMS]
  float* out_idxf = out + 2 + QELEMS;     // [2+QELEMS ..)

  char* ws = (char*)d_ws;
  int*    w_idx = (int*)ws;
  double* w_lp  = (double*)(ws + 524288);
  int*    w_cnt = (int*)(ws + 524288 + 16384);
  size_t pers = 524288 + 16384 + 128;

  const size_t SZ_XFR  = 134217728;                // xfrag bf16
  const size_t SZ_EFR  = 524288;
  const size_t SZ_SENP = 2048;
  const size_t SZ_RCNT = 256;                      // rcnt + ocnt
  const size_t SZ_RROW = (size_t)RFCAP * 4;
  const size_t SZ_OLST = (size_t)RFCAP * 4;
  const size_t SZ_ET   = (size_t)K_ * C_ * 4;      // 1 MB
  const size_t SZ_CCNT = (size_t)N_ * 4;           // 512 KB
  const size_t SZ_CAND = (size_t)N_ * MAXC * 4;    // 8 MB
  const size_t SZ_XT   = (size_t)N_ * C_ * 4;      // 268 MB
  const size_t VOL_SMALL = SZ_XFR + SZ_EFR + SZ_SENP + SZ_RCNT + SZ_RROW +
                           SZ_OLST + SZ_ET + SZ_CCNT + SZ_CAND;
  const size_t VOL_BIG   = VOL_SMALL + SZ_XT;

  char* vbase;
  float* w_xT = nullptr;
  if (ws_size >= pers + VOL_BIG + 4096) {
    vbase = ws + ((pers + 255) & ~(size_t)255);
    w_xT  = (float*)(vbase + VOL_SMALL);
  } else if (ws_size >= pers + VOL_SMALL + 4096) {
    vbase = ws + ((pers + 255) & ~(size_t)255);
  } else {
    uintptr_t a = ((uintptr_t)(out_q + QELEMS) - VOL_SMALL) & ~(uintptr_t)255;
    vbase = (char*)a;
  }
  char* p = vbase;
  ushort* w_xfr  = (ushort*)p;            p += SZ_XFR;
  ushort* w_efr  = (ushort*)p;            p += SZ_EFR;
  float*  w_senp = (float*)p;             p += SZ_SENP;
  int*    w_rcnt = (int*)p;
  int*    w_ocnt = (int*)(p + 128);       p += SZ_RCNT;
  int*    w_rrows= (int*)p;               p += SZ_RROW;
  int*    w_olst = (int*)p;               p += SZ_OLST;
  float*  w_eT   = (float*)p;             p += SZ_ET;
  int*    w_ccnt = (int*)p;               p += SZ_CCNT;
  int*    w_cand = (int*)p;               p += SZ_CAND;

  k_prep  <<<dim3(512),   dim3(256), 0, stream>>>(embed, w_senp, w_eT, w_rcnt, w_ocnt, w_ccnt);
  k_epack <<<dim3(16),    dim3(256), 0, stream>>>(embed, w_efr);
  k_xsplit<<<dim3(16384), dim3(256), 0, stream>>>(x, w_xfr, w_xT);
  k_argmin<<<dim3(2048),  dim3(512), 0, stream>>>(w_xfr, w_efr, w_senp, w_idx, w_rcnt, w_rrows, w_ccnt, w_cand);
  k_refine<<<dim3(2048),  dim3(256), 0, stream>>>(x, w_xT, embed, w_senp, w_rcnt, w_rrows, w_ccnt, w_cand, w_ocnt, w_olst, w_idx);
  k_refine_full<<<dim3(256), dim3(512), 0, stream>>>(x, w_xT, w_eT, w_senp, w_ocnt, w_olst, w_idx);
  k_gather<<<dim3(1024),  dim3(256), 0, stream>>>(x, embed, w_idx, out_q, w_lp);
  k_pplx  <<<dim3(32),    dim3(256), 0, stream>>>(w_idx, out_idxf, w_cnt);
  k_final <<<dim3(1),     dim3(256), 0, stream>>>(w_lp, w_cnt, out_loss, out_pplx);
}

// Round 19
// 523.132 us; speedup vs baseline: 1.0746x; 1.0746x over previous
//
#include <hip/hip_runtime.h>
#include <stdint.h>

#define B_ 32
#define C_ 512
#define HW_ 4096
#define N_ 131072
#define K_ 512
#define QELEMS 67108864   /* B*C*H*W = 2^26 */
#define MARGIN 1e-3f
#define CAND   2.5e-3f
#define MAXC   16
#define RFCAP 131072      /* == N_: refine list can never overflow */

typedef __attribute__((ext_vector_type(8)))  short bf16x8;
typedef __attribute__((ext_vector_type(16))) float f32x16;

__device__ __forceinline__ ushort f2bf(float f) {   // RNE f32->bf16 (no NaN inputs)
  uint u = __float_as_uint(f);
  return (ushort)((u + 0x7FFFu + ((u >> 16) & 1u)) >> 16);
}

// ---------------------------------------------------------------------------
// numpy float32 pairwise sum of 512 floats (AVX512 base case, 8 vec accs,
// GCC _mm512_reduce_add_ps horizontal tree).
// ---------------------------------------------------------------------------
__device__ __forceinline__ float np_pw512(const float* a) {
  float P[4];
#pragma unroll
  for (int m = 0; m < 4; ++m) {
    const float* q = a + m * 128;
    float rv[16];
#pragma unroll
    for (int l = 0; l < 16; ++l) {
      float v0 = q[l],      v1 = q[16 + l],  v2 = q[32 + l],  v3 = q[48 + l];
      float v4 = q[64 + l], v5 = q[80 + l],  v6 = q[96 + l],  v7 = q[112 + l];
      rv[l] = ((v0 + v1) + (v2 + v3)) + ((v4 + v5) + (v6 + v7));
    }
    float u[8], w[4];
#pragma unroll
    for (int l = 0; l < 8; ++l) u[l] = rv[8 + l] + rv[l];
#pragma unroll
    for (int l = 0; l < 4; ++l) w[l] = u[4 + l] + u[l];
    P[m] = (w[0] + w[2]) + (w[1] + w[3]);
  }
  return (P[0] + P[1]) + (P[2] + P[3]);
}

// Same tree over squared elements (sq computed with __fmul_rn, as np does).
__device__ __forceinline__ float np_pw512_sq(const float* a) {
  float P[4];
#pragma unroll
  for (int m = 0; m < 4; ++m) {
    const float* q = a + m * 128;
    float rv[16];
#pragma unroll
    for (int l = 0; l < 16; ++l) {
      float v0 = __fmul_rn(q[l], q[l]);
      float v1 = __fmul_rn(q[16 + l], q[16 + l]);
      float v2 = __fmul_rn(q[32 + l], q[32 + l]);
      float v3 = __fmul_rn(q[48 + l], q[48 + l]);
      float v4 = __fmul_rn(q[64 + l], q[64 + l]);
      float v5 = __fmul_rn(q[80 + l], q[80 + l]);
      float v6 = __fmul_rn(q[96 + l], q[96 + l]);
      float v7 = __fmul_rn(q[112 + l], q[112 + l]);
      rv[l] = ((v0 + v1) + (v2 + v3)) + ((v4 + v5) + (v6 + v7));
    }
    float u[8], w[4];
#pragma unroll
    for (int l = 0; l < 8; ++l) u[l] = rv[8 + l] + rv[l];
#pragma unroll
    for (int l = 0; l < 4; ++l) w[l] = u[4 + l] + u[l];
    P[m] = (w[0] + w[2]) + (w[1] + w[3]);
  }
  return (P[0] + P[1]) + (P[2] + P[3]);
}

// ---------------------------------------------------------------------------
// K0: senp[k]; eT[c][k]; zero rcnt/ocnt and candCnt[N].
// ---------------------------------------------------------------------------
__global__ __launch_bounds__(256) void k_prep(const float* __restrict__ embed,
    float* __restrict__ senp, float* __restrict__ eT, int* __restrict__ rcnt,
    int* __restrict__ ocnt, int* __restrict__ candCnt)
{
  __shared__ float sqa[C_];
  int k = blockIdx.x;
  candCnt[blockIdx.x * 256 + threadIdx.x] = 0;   // 512*256 == N_
  for (int c = threadIdx.x; c < C_; c += 256) {
    float e = embed[k * C_ + c];
    eT[c * K_ + k] = e;
    sqa[c] = __fmul_rn(e, e);
  }
  __syncthreads();
  if (threadIdx.x == 0) {
    senp[k] = np_pw512(sqa);
    if (blockIdx.x == 0) { *rcnt = 0; *ocnt = 0; }
  }
}

// ---------------------------------------------------------------------------
// K0a: pack embed -> efrag fragment-major (unchanged, verified).
// ---------------------------------------------------------------------------
__global__ __launch_bounds__(256) void k_epack(const float* __restrict__ embed,
    ushort* __restrict__ efrag)
{
  const int cb = blockIdx.x;
  const int t = threadIdx.x;
  const int lane = t & 63, ksq = t >> 6;
  const int l31 = lane & 31, lhi = lane >> 5;
  const float* ep = embed + ((size_t)(cb * 32 + l31) << 9) + lhi * 8;
#pragma unroll
  for (int i = 0; i < 8; ++i) {
    int ks = ksq * 8 + i;
    float4 v0 = *(const float4*)(ep + ks * 16);
    float4 v1 = *(const float4*)(ep + ks * 16 + 4);
    uint u0 = (uint)f2bf(v0.x) | ((uint)f2bf(v0.y) << 16);
    uint u1 = (uint)f2bf(v0.z) | ((uint)f2bf(v0.w) << 16);
    uint u2 = (uint)f2bf(v1.x) | ((uint)f2bf(v1.y) << 16);
    uint u3 = (uint)f2bf(v1.z) | ((uint)f2bf(v1.w) << 16);
    ushort* op = efrag + (((size_t)(cb * 32 + ks)) * 64 + lane) * 8;
    *(uint4*)op = make_uint4(u0, u1, u2, u3);
  }
}

// ---------------------------------------------------------------------------
// K0b: x -> xfrag (bf16 fragment-major) + optional xT [b][hw][c] f32.
//      Unchanged, verified.
// ---------------------------------------------------------------------------
__global__ __launch_bounds__(256) void k_xsplit(const float* __restrict__ x,
    ushort* __restrict__ xfrag, float* __restrict__ xT)
{
  __shared__ float tile[64][66];
  const int bid = blockIdx.x;
  const int ht = bid & 63, ct = (bid >> 6) & 7, b = bid >> 9;
  const int t = threadIdx.x;
  const int r = t & 63, cq = t >> 6;
  const float* xp = x + (((size_t)(b * C_ + ct * 64)) << 12) + ht * 64 + r;
#pragma unroll
  for (int i = 0; i < 16; ++i) {
    int c = cq * 16 + i;
    tile[r][c] = xp[(size_t)c << 12];
  }
  __syncthreads();
  const int lane = t & 63, ksl = t >> 6;
  const int l31 = lane & 31, lhi = lane >> 5;
  const int ks = ct * 4 + ksl;
  const int cc = ksl * 16 + lhi * 8;
#pragma unroll
  for (int rbl = 0; rbl < 2; ++rbl) {
    int rr = rbl * 32 + l31;
    uint u[4];
#pragma unroll
    for (int j = 0; j < 4; ++j) {
      float f0 = tile[rr][cc + 2 * j];
      float f1 = tile[rr][cc + 2 * j + 1];
      u[j] = (uint)f2bf(f0) | ((uint)f2bf(f1) << 16);
    }
    size_t rb = (size_t)b * 128 + ht * 2 + rbl;
    ushort* op = xfrag + ((rb * 32 + ks) * 64 + lane) * 8;
    *(uint4*)op = make_uint4(u[0], u[1], u[2], u[3]);
  }
  if (xT) {
    const int r2 = t >> 2, cs2 = (t & 3) << 4;
    float* op = xT + ((size_t)(b * HW_ + ht * 64 + r2) << 9) + ct * 64 + cs2;
#pragma unroll
    for (int j = 0; j < 4; ++j) {
      float4 v;
      v.x = tile[r2][cs2 + 4 * j + 0];
      v.y = tile[r2][cs2 + 4 * j + 1];
      v.z = tile[r2][cs2 + 4 * j + 2];
      v.w = tile[r2][cs2 + 4 * j + 3];
      *(float4*)(op + 4 * j) = v;
    }
  }
}

// ---------------------------------------------------------------------------
// K1: MFMA argmin, 2x4 tile + LDS double-buffered async staging (the
//     best-measured end-to-end configuration, round 15: 524.7 us total).
// ---------------------------------------------------------------------------
__global__ __launch_bounds__(512, 2) void k_argmin(const ushort* __restrict__ xfrag,
    const ushort* __restrict__ efrag, const float* __restrict__ senp,
    int* __restrict__ idx_out, int* __restrict__ rcnt, int* __restrict__ rrows,
    int* __restrict__ candCnt, int* __restrict__ cand)
{
  __shared__ float ses[K_];
  __shared__ float mbL[128][4], msL[128][4];
  __shared__ int   miL[128][4];
  __shared__ float rowBest[128];
  __shared__ int   rowFlag[128];
  __shared__ __align__(16) ushort stg[2 * 20 * 512];   // 2 x 20KB staging
  const int t = threadIdx.x;
  const int lane = t & 63, wid = t >> 6;
  const int wc = wid & 3, wr = wid >> 2;
  const int l31 = lane & 31, lhi = lane >> 5;
  const int bid = blockIdx.x;

  for (int i = t; i < K_; i += 512) ses[i] = senp[i];

  // staging sources: wave wid owns chunks {wid, wid+8, wid+16(<20)}
  //   chunk c<4  -> x row-block bid*4+c ; chunk c>=4 -> e chain c-4
  const ushort* g0 = (wid < 4)
      ? xfrag + ((size_t)(bid * 4 + wid) * 2048 + lane) * 8
      : efrag + ((size_t)(wid - 4) * 2048 + lane) * 8;
  const ushort* g1 = efrag + ((size_t)(wid + 4) * 2048 + lane) * 8;   // chunk wid+8
  const ushort* g2 = efrag + ((size_t)(wid + 12) * 2048 + lane) * 8;  // chunk wid+16

  auto GLL = [&](const ushort* gp, int lofs) {
    __builtin_amdgcn_global_load_lds(
        (const __attribute__((address_space(1))) uint32_t*)gp,
        (__attribute__((address_space(3))) uint32_t*)&stg[lofs], 16, 0, 0);
  };

  // prologue: stage ks=0 into buffer 0
  GLL(g0, wid * 512);
  GLL(g1, (wid + 8) * 512);
  if (wid < 4) GLL(g2, (wid + 16) * 512);
  __syncthreads();

  f32x16 z = {0,0,0,0,0,0,0,0,0,0,0,0,0,0,0,0};
  f32x16 a00 = z, a01 = z, a02 = z, a03 = z;
  f32x16 a10 = z, a11 = z, a12 = z, a13 = z;

  for (int ks = 0; ks < 32; ++ks) {
    const int cur = ks & 1;
    if (ks + 1 < 32) {                       // issue next-step staging first
      const size_t so = (size_t)(ks + 1) * 512;   // +1KB per ks in each chunk
      const int bo = (cur ^ 1) * (20 * 512);
      GLL(g0 + so, bo + wid * 512);
      GLL(g1 + so, bo + (wid + 8) * 512);
      if (wid < 4) GLL(g2 + so, bo + (wid + 16) * 512);
    }
    const ushort* bp = &stg[cur * (20 * 512)];
    bf16x8 x0 = *(const bf16x8*)(bp + (wr * 2 + 0) * 512 + lane * 8);
    bf16x8 x1 = *(const bf16x8*)(bp + (wr * 2 + 1) * 512 + lane * 8);
    bf16x8 e0 = *(const bf16x8*)(bp + (4 + wc * 4 + 0) * 512 + lane * 8);
    bf16x8 e1 = *(const bf16x8*)(bp + (4 + wc * 4 + 1) * 512 + lane * 8);
    bf16x8 e2 = *(const bf16x8*)(bp + (4 + wc * 4 + 2) * 512 + lane * 8);
    bf16x8 e3 = *(const bf16x8*)(bp + (4 + wc * 4 + 3) * 512 + lane * 8);
    __builtin_amdgcn_s_setprio(1);
    a00 = __builtin_amdgcn_mfma_f32_32x32x16_bf16(e0, x0, a00, 0, 0, 0);
    a01 = __builtin_amdgcn_mfma_f32_32x32x16_bf16(e1, x0, a01, 0, 0, 0);
    a02 = __builtin_amdgcn_mfma_f32_32x32x16_bf16(e2, x0, a02, 0, 0, 0);
    a03 = __builtin_amdgcn_mfma_f32_32x32x16_bf16(e3, x0, a03, 0, 0, 0);
    a10 = __builtin_amdgcn_mfma_f32_32x32x16_bf16(e0, x1, a10, 0, 0, 0);
    a11 = __builtin_amdgcn_mfma_f32_32x32x16_bf16(e1, x1, a11, 0, 0, 0);
    a12 = __builtin_amdgcn_mfma_f32_32x32x16_bf16(e2, x1, a12, 0, 0, 0);
    a13 = __builtin_amdgcn_mfma_f32_32x32x16_bf16(e3, x1, a13, 0, 0, 0);
    __builtin_amdgcn_s_setprio(0);
    __syncthreads();   // drains vmcnt (next buffer staged) + frees cur buffer
  }

  // per-lane top-2, x-stream 0
  float b0 = 1e30f, s0 = 1e30f; int i0 = 0;
#pragma unroll
  for (int r = 0; r < 16; ++r) {
    int crow = (r & 3) + 8 * (r >> 2) + 4 * lhi;
    float v; int code;
    code = wc * 128 + 0  + crow; v = ses[code] - 2.0f * a00[r];
    if (v < b0 || (v == b0 && code < i0)) { s0 = b0; b0 = v; i0 = code; }
    else if (v < s0) s0 = v;
    code = wc * 128 + 32 + crow; v = ses[code] - 2.0f * a01[r];
    if (v < b0 || (v == b0 && code < i0)) { s0 = b0; b0 = v; i0 = code; }
    else if (v < s0) s0 = v;
    code = wc * 128 + 64 + crow; v = ses[code] - 2.0f * a02[r];
    if (v < b0 || (v == b0 && code < i0)) { s0 = b0; b0 = v; i0 = code; }
    else if (v < s0) s0 = v;
    code = wc * 128 + 96 + crow; v = ses[code] - 2.0f * a03[r];
    if (v < b0 || (v == b0 && code < i0)) { s0 = b0; b0 = v; i0 = code; }
    else if (v < s0) s0 = v;
  }
  // per-lane top-2, x-stream 1
  float b1 = 1e30f, s1 = 1e30f; int i1 = 0;
#pragma unroll
  for (int r = 0; r < 16; ++r) {
    int crow = (r & 3) + 8 * (r >> 2) + 4 * lhi;
    float v; int code;
    code = wc * 128 + 0  + crow; v = ses[code] - 2.0f * a10[r];
    if (v < b1 || (v == b1 && code < i1)) { s1 = b1; b1 = v; i1 = code; }
    else if (v < s1) s1 = v;
    code = wc * 128 + 32 + crow; v = ses[code] - 2.0f * a11[r];
    if (v < b1 || (v == b1 && code < i1)) { s1 = b1; b1 = v; i1 = code; }
    else if (v < s1) s1 = v;
    code = wc * 128 + 64 + crow; v = ses[code] - 2.0f * a12[r];
    if (v < b1 || (v == b1 && code < i1)) { s1 = b1; b1 = v; i1 = code; }
    else if (v < s1) s1 = v;
    code = wc * 128 + 96 + crow; v = ses[code] - 2.0f * a13[r];
    if (v < b1 || (v == b1 && code < i1)) { s1 = b1; b1 = v; i1 = code; }
    else if (v < s1) s1 = v;
  }
  // pre-merge copies for candidate collection
  const float pb0 = b0, ps0 = s0; const int pi0 = i0;
  const float pb1 = b1, ps1 = s1; const int pi1 = i1;
  // cross-half-wave merges (lanes l and l+32 share a row)
  {
    float ob = __shfl_xor(b0, 32, 64), os = __shfl_xor(s0, 32, 64);
    int   oi = __shfl_xor(i0, 32, 64);
    float ns = fminf(fmaxf(b0, ob), fminf(s0, os));
    if (ob < b0 || (ob == b0 && oi < i0)) { b0 = ob; i0 = oi; }
    s0 = ns;
  }
  {
    float ob = __shfl_xor(b1, 32, 64), os = __shfl_xor(s1, 32, 64);
    int   oi = __shfl_xor(i1, 32, 64);
    float ns = fminf(fmaxf(b1, ob), fminf(s1, os));
    if (ob < b1 || (ob == b1 && oi < i1)) { b1 = ob; i1 = oi; }
    s1 = ns;
  }
  if (lane < 32) {
    int rr0 = (wr * 2 + 0) * 32 + l31;
    int rr1 = (wr * 2 + 1) * 32 + l31;
    mbL[rr0][wc] = b0; msL[rr0][wc] = s0; miL[rr0][wc] = i0;
    mbL[rr1][wc] = b1; msL[rr1][wc] = s1; miL[rr1][wc] = i1;
  }
  __syncthreads();
  if (t < 128) {
    float Bv = 1e30f, Sv = 1e30f; int Iv = 0;
#pragma unroll
    for (int q = 0; q < 4; ++q) {
      float bq = mbL[t][q], sq = msL[t][q]; int iq = miL[t][q];
      if (bq < Bv || (bq == Bv && iq < Iv)) { Sv = fminf(Bv, sq); Bv = bq; Iv = iq; }
      else Sv = fminf(Sv, bq);
    }
    int n = bid * 128 + t;
    idx_out[n] = Iv;
    rowBest[t] = Bv;
    int fl = (Sv - Bv < MARGIN) ? 1 : 0;
    rowFlag[t] = fl;
    if (fl) {
      int p = atomicAdd(rcnt, 1);
      if (p < RFCAP) rrows[p] = n;
    }
  }
  __syncthreads();
  // candidate collection (cheap path + rare full rescan), per x-stream
  {
    const int rr0 = (wr * 2 + 0) * 32 + l31;
    if (rowFlag[rr0]) {
      const float thr = rowBest[rr0] + CAND;
      const int n = bid * 128 + rr0;
      if (pb0 <= thr) {
        int p = atomicAdd(&candCnt[n], 1);
        if (p < MAXC) cand[(size_t)n * MAXC + p] = pi0;
      }
      if (ps0 <= thr) {
#pragma unroll
        for (int r = 0; r < 16; ++r) {
          int crow = (r & 3) + 8 * (r >> 2) + 4 * lhi;
          float v; int code;
          code = wc * 128 + 0  + crow; v = ses[code] - 2.0f * a00[r];
          if (v <= thr && code != pi0) { int p = atomicAdd(&candCnt[n], 1); if (p < MAXC) cand[(size_t)n * MAXC + p] = code; }
          code = wc * 128 + 32 + crow; v = ses[code] - 2.0f * a01[r];
          if (v <= thr && code != pi0) { int p = atomicAdd(&candCnt[n], 1); if (p < MAXC) cand[(size_t)n * MAXC + p] = code; }
          code = wc * 128 + 64 + crow; v = ses[code] - 2.0f * a02[r];
          if (v <= thr && code != pi0) { int p = atomicAdd(&candCnt[n], 1); if (p < MAXC) cand[(size_t)n * MAXC + p] = code; }
          code = wc * 128 + 96 + crow; v = ses[code] - 2.0f * a03[r];
          if (v <= thr && code != pi0) { int p = atomicAdd(&candCnt[n], 1); if (p < MAXC) cand[(size_t)n * MAXC + p] = code; }
        }
      }
    }
    const int rr1 = (wr * 2 + 1) * 32 + l31;
    if (rowFlag[rr1]) {
      const float thr = rowBest[rr1] + CAND;
      const int n = bid * 128 + rr1;
      if (pb1 <= thr) {
        int p = atomicAdd(&candCnt[n], 1);
        if (p < MAXC) cand[(size_t)n * MAXC + p] = pi1;
      }
      if (ps1 <= thr) {
#pragma unroll
        for (int r = 0; r < 16; ++r) {
          int crow = (r & 3) + 8 * (r >> 2) + 4 * lhi;
          float v; int code;
          code = wc * 128 + 0  + crow; v = ses[code] - 2.0f * a10[r];
          if (v <= thr && code != pi1) { int p = atomicAdd(&candCnt[n], 1); if (p < MAXC) cand[(size_t)n * MAXC + p] = code; }
          code = wc * 128 + 32 + crow; v = ses[code] - 2.0f * a11[r];
          if (v <= thr && code != pi1) { int p = atomicAdd(&candCnt[n], 1); if (p < MAXC) cand[(size_t)n * MAXC + p] = code; }
          code = wc * 128 + 64 + crow; v = ses[code] - 2.0f * a12[r];
          if (v <= thr && code != pi1) { int p = atomicAdd(&candCnt[n], 1); if (p < MAXC) cand[(size_t)n * MAXC + p] = code; }
          code = wc * 128 + 96 + crow; v = ses[code] - 2.0f * a13[r];
          if (v <= thr && code != pi1) { int p = atomicAdd(&candCnt[n], 1); if (p < MAXC) cand[(size_t)n * MAXC + p] = code; }
        }
      }
    }
  }
}

// ---------------------------------------------------------------------------
// K2: candidate refine. 4 rows/block (wave per row); lane = candidate.
// ---------------------------------------------------------------------------
__global__ __launch_bounds__(256) void k_refine(const float* __restrict__ x,
    const float* __restrict__ xT, const float* __restrict__ embed,
    const float* __restrict__ senp,
    const int* __restrict__ rcnt, const int* __restrict__ rrows,
    const int* __restrict__ candCnt, const int* __restrict__ cand,
    int* __restrict__ ocnt, int* __restrict__ olist,
    int* __restrict__ idx_out)
{
  __shared__ float xls[4][516];
  __shared__ float SxSh[4];
  __shared__ int   nrow[4];
  const int t = threadIdx.x;
  const int lane = t & 63, w = t >> 6;
  int cnt = *rcnt; if (cnt > RFCAP) cnt = RFCAP;
  for (int base = blockIdx.x * 4; base < cnt; base += gridDim.x * 4) {
    __syncthreads();
    if (t < 4) {
      int i = base + t;
      nrow[t] = rrows[i < cnt ? i : base];
    }
    __syncthreads();
    if (xT) {
      for (int i = t; i < 4 * C_; i += 256) {
        int s = i >> 9, c = i & 511;
        xls[s][c] = xT[((size_t)nrow[s] << 9) + c];
      }
    } else {
      for (int i = t; i < 4 * C_; i += 256) {
        int s = i >> 9, c = i & 511;
        int n = nrow[s];
        int b = n >> 12, hw = n & 4095;
        xls[s][c] = x[(((size_t)(b * C_ + c)) << 12) + hw];
      }
    }
    __syncthreads();
    if (t < 4) SxSh[t] = np_pw512_sq(&xls[t][0]);
    __syncthreads();
    const int n = nrow[w];
    const int cc = candCnt[n];
    float d = 1e30f; int code = 0x7fffffff;
    if (cc <= MAXC) {
      if (lane < cc) {
        code = cand[(size_t)n * MAXC + lane];
        const float* e = embed + (size_t)code * C_;
        const float* xr = &xls[w][0];
        float s1 = 0.f, s2 = 0.f;
        for (int c = 0; c < 384; ++c)  s1 = fmaf(xr[c], e[c], s1);
        for (int c = 384; c < 512; ++c) s2 = fmaf(xr[c], e[c], s2);
        float M = s1 + s2;
        d = (SxSh[w] + senp[code]) - 2.0f * M;
      }
#pragma unroll
      for (int off = 1; off < 16; off <<= 1) {
        float ov = __shfl_xor(d, off, 64);
        int   oc = __shfl_xor(code, off, 64);
        if (ov < d || (ov == d && oc < code)) { d = ov; code = oc; }
      }
      if (lane == 0 && base + w < cnt) idx_out[n] = code;
    } else {
      if (lane == 0 && base + w < cnt) {
        int p = atomicAdd(ocnt, 1);
        if (p < RFCAP) olist[p] = n;
      }
    }
  }
}

// ---------------------------------------------------------------------------
// K2b: full 512-code np-replica re-rank — overflow fallback (normally 0 rows).
// ---------------------------------------------------------------------------
__global__ __launch_bounds__(512) void k_refine_full(const float* __restrict__ x,
    const float* __restrict__ xT, const float* __restrict__ eT,
    const float* __restrict__ senp,
    const int* __restrict__ rcnt, const int* __restrict__ rrows,
    int* __restrict__ idx_out)
{
  __shared__ float xls[8][520];
  __shared__ float SxSh[8];
  __shared__ int   nrow[8];
  __shared__ float wval[8][8];
  __shared__ int   widx[8][8];
  const int t = threadIdx.x;
  const int lane = t & 63, w = t >> 6;
  int cnt = *rcnt; if (cnt > RFCAP) cnt = RFCAP;
  for (int base = blockIdx.x * 8; base < cnt; base += gridDim.x * 8) {
    __syncthreads();
    if (t < 8) {
      int i = base + t;
      nrow[t] = rrows[i < cnt ? i : base];
    }
    __syncthreads();
    if (xT) {
#pragma unroll
      for (int rr = 0; rr < 8; ++rr)
        xls[rr][t] = xT[((size_t)nrow[rr] << 9) + t];
    } else {
#pragma unroll
      for (int rr = 0; rr < 8; ++rr) {
        int n = nrow[rr];
        int b = n >> 12, hw = n & 4095;
        xls[rr][t] = x[(((size_t)(b * C_ + t)) << 12) + hw];
      }
    }
    __syncthreads();
    if (t < 8) SxSh[t] = np_pw512_sq(&xls[t][0]);
    __syncthreads();
    const float* ep = eT + t;
    float a1[8], a2[8];
#pragma unroll
    for (int rr = 0; rr < 8; ++rr) { a1[rr] = 0.f; a2[rr] = 0.f; }
    for (int c4 = 0; c4 < 384; c4 += 4) {
      float e0 = ep[(size_t)(c4 + 0) << 9];
      float e1 = ep[(size_t)(c4 + 1) << 9];
      float e2 = ep[(size_t)(c4 + 2) << 9];
      float e3 = ep[(size_t)(c4 + 3) << 9];
#pragma unroll
      for (int rr = 0; rr < 8; ++rr) {
        float4 xv = *(const float4*)&xls[rr][c4];
        a1[rr] = fmaf(xv.x, e0, a1[rr]);
        a1[rr] = fmaf(xv.y, e1, a1[rr]);
        a1[rr] = fmaf(xv.z, e2, a1[rr]);
        a1[rr] = fmaf(xv.w, e3, a1[rr]);
      }
    }
    for (int c4 = 384; c4 < 512; c4 += 4) {
      float e0 = ep[(size_t)(c4 + 0) << 9];
      float e1 = ep[(size_t)(c4 + 1) << 9];
      float e2 = ep[(size_t)(c4 + 2) << 9];
      float e3 = ep[(size_t)(c4 + 3) << 9];
#pragma unroll
      for (int rr = 0; rr < 8; ++rr) {
        float4 xv = *(const float4*)&xls[rr][c4];
        a2[rr] = fmaf(xv.x, e0, a2[rr]);
        a2[rr] = fmaf(xv.y, e1, a2[rr]);
        a2[rr] = fmaf(xv.z, e2, a2[rr]);
        a2[rr] = fmaf(xv.w, e3, a2[rr]);
      }
    }
    float se = senp[t];
    float bv[8]; int bi[8];
#pragma unroll
    for (int rr = 0; rr < 8; ++rr) {
      float M = a1[rr] + a2[rr];
      bv[rr] = (SxSh[rr] + se) - 2.0f * M;
      bi[rr] = t;
    }
#pragma unroll
    for (int off = 1; off < 64; off <<= 1) {
#pragma unroll
      for (int rr = 0; rr < 8; ++rr) {
        float ov = __shfl_xor(bv[rr], off, 64);
        int   oi = __shfl_xor(bi[rr], off, 64);
        if (ov < bv[rr] || (ov == bv[rr] && oi < bi[rr])) { bv[rr] = ov; bi[rr] = oi; }
      }
    }
    if (lane == 0) {
#pragma unroll
      for (int rr = 0; rr < 8; ++rr) { wval[w][rr] = bv[rr]; widx[w][rr] = bi[rr]; }
    }
    __syncthreads();
    if (t < 8) {
      float Bv = wval[0][t]; int Iv = widx[0][t];
#pragma unroll
      for (int q = 1; q < 8; ++q) {
        float ov = wval[q][t]; int oi = widx[q][t];
        if (ov < Bv || (ov == Bv && oi < Iv)) { Bv = ov; Iv = oi; }
      }
      if (base + t < cnt) idx_out[nrow[t]] = Iv;
    }
  }
}

// ---------------------------------------------------------------------------
// K3: gather + loss (unchanged).
// ---------------------------------------------------------------------------
__global__ __launch_bounds__(256) void k_gather(const float* __restrict__ x,
    const float* __restrict__ embed, const int* __restrict__ idx,
    float* __restrict__ out_q, double* __restrict__ loss_part)
{
  __shared__ float ecol[32][512];
  const int bid = blockIdx.x;
  const int hch = bid & 1, cch = (bid >> 1) & 15, b = bid >> 5;
  const int c0 = cch * 32, hw0 = hch * 2048;
  const int t = threadIdx.x;
  for (int i = t; i < 512 * 32; i += 256) {
    int c = i & 31, k = i >> 5;
    ecol[c][(k + c0 + c) & 511] = embed[((size_t)k << 9) + c0 + c];
  }
  __syncthreads();
  int kreg[8];
#pragma unroll
  for (int j = 0; j < 8; ++j)
    kreg[j] = idx[(b << 12) + hw0 + t + 256 * j];
  double s = 0.0;
  for (int c = 0; c < 32; ++c) {
    const float* xrow = x + (((size_t)(b * C_ + c0 + c)) << 12) + hw0;
    float* orow = out_q + (((size_t)(b * C_ + c0 + c)) << 12) + hw0;
#pragma unroll
    for (int j = 0; j < 8; ++j) {
      float q  = ecol[c][(kreg[j] + c0 + c) & 511];
      float xv = xrow[t + 256 * j];
      orow[t + 256 * j] = q;
      double d = (double)q - (double)xv;
      s += d * d;
    }
  }
  for (int off = 32; off > 0; off >>= 1) s += __shfl_down(s, off, 64);
  __shared__ double wsum[4];
  if ((t & 63) == 0) wsum[t >> 6] = s;
  __syncthreads();
  if (t == 0)
    loss_part[bid] = (wsum[0] + wsum[1]) + (wsum[2] + wsum[3]);
}

// ---------------------------------------------------------------------------
// K4: per-batch unique-code count + write idx_b as float.
// ---------------------------------------------------------------------------
__global__ __launch_bounds__(256) void k_pplx(const int* __restrict__ idx,
    float* __restrict__ out_idxf, int* __restrict__ counts)
{
  __shared__ int flags[K_];
  __shared__ int red[256];
  int b = blockIdx.x;
  for (int i = threadIdx.x; i < K_; i += 256) flags[i] = 0;
  __syncthreads();
  for (int hw = threadIdx.x; hw < HW_; hw += 256) {
    int k = idx[(b << 12) + hw];
    flags[k] = 1;
    out_idxf[(b << 12) + hw] = (float)k;
  }
  __syncthreads();
  int c = 0;
  for (int i = threadIdx.x; i < K_; i += 256) c += flags[i];
  red[threadIdx.x] = c;
  __syncthreads();
  for (int st = 128; st > 0; st >>= 1) {
    if (threadIdx.x < st) red[threadIdx.x] += red[threadIdx.x + st];
    __syncthreads();
  }
  if (threadIdx.x == 0) counts[b] = red[0];
}

// ---------------------------------------------------------------------------
// K5: finalize scalars (1024 loss partials).
// ---------------------------------------------------------------------------
__global__ __launch_bounds__(256) void k_final(const double* __restrict__ loss_part,
    const int* __restrict__ counts, float* __restrict__ out_loss,
    float* __restrict__ out_pplx)
{
  __shared__ double sred[256];
  double s = 0.0;
  for (int i = threadIdx.x; i < 1024; i += 256) s += loss_part[i];
  sred[threadIdx.x] = s;
  __syncthreads();
  for (int st = 128; st > 0; st >>= 1) {
    if (threadIdx.x < st) sred[threadIdx.x] += sred[threadIdx.x + st];
    __syncthreads();
  }
  if (threadIdx.x == 0) {
    *out_loss = (float)(1.25 * sred[0] / (double)QELEMS);
    int c = 0;
    for (int i = 0; i < B_; ++i) c += counts[i];
    *out_pplx = (float)c / (float)B_;
  }
}

// ---------------------------------------------------------------------------
extern "C" void kernel_launch(void* const* d_in, const int* in_sizes, int n_in,
                              void* d_out, int out_size, void* d_ws, size_t ws_size,
                              hipStream_t stream)
{
  const float* x     = (const float*)d_in[0];
  const float* embed = (const float*)d_in[1];
  float* out      = (float*)d_out;
  float* out_loss = out;                  // [0]
  float* out_q    = out + 1;              // [1 .. 1+QELEMS)
  float* out_pplx = out + 1 + QELEMS;     // [1+QELEMS]
  float* out_idxf = out + 2 + QELEMS;     // [2+QELEMS ..)

  char* ws = (char*)d_ws;
  int*    w_idx = (int*)ws;
  double* w_lp  = (double*)(ws + 524288);
  int*    w_cnt = (int*)(ws + 524288 + 16384);
  size_t pers = 524288 + 16384 + 128;

  const size_t SZ_XFR  = 134217728;                // xfrag bf16
  const size_t SZ_EFR  = 524288;
  const size_t SZ_SENP = 2048;
  const size_t SZ_RCNT = 256;                      // rcnt + ocnt
  const size_t SZ_RROW = (size_t)RFCAP * 4;
  const size_t SZ_OLST = (size_t)RFCAP * 4;
  const size_t SZ_ET   = (size_t)K_ * C_ * 4;      // 1 MB
  const size_t SZ_CCNT = (size_t)N_ * 4;           // 512 KB
  const size_t SZ_CAND = (size_t)N_ * MAXC * 4;    // 8 MB
  const size_t SZ_XT   = (size_t)N_ * C_ * 4;      // 268 MB
  const size_t VOL_SMALL = SZ_XFR + SZ_EFR + SZ_SENP + SZ_RCNT + SZ_RROW +
                           SZ_OLST + SZ_ET + SZ_CCNT + SZ_CAND;
  const size_t VOL_BIG   = VOL_SMALL + SZ_XT;

  char* vbase;
  float* w_xT = nullptr;
  if (ws_size >= pers + VOL_BIG + 4096) {
    vbase = ws + ((pers + 255) & ~(size_t)255);
    w_xT  = (float*)(vbase + VOL_SMALL);
  } else if (ws_size >= pers + VOL_SMALL + 4096) {
    vbase = ws + ((pers + 255) & ~(size_t)255);
  } else {
    uintptr_t a = ((uintptr_t)(out_q + QELEMS) - VOL_SMALL) & ~(uintptr_t)255;
    vbase = (char*)a;
  }
  char* p = vbase;
  ushort* w_xfr  = (ushort*)p;            p += SZ_XFR;
  ushort* w_efr  = (ushort*)p;            p += SZ_EFR;
  float*  w_senp = (float*)p;             p += SZ_SENP;
  int*    w_rcnt = (int*)p;
  int*    w_ocnt = (int*)(p + 128);       p += SZ_RCNT;
  int*    w_rrows= (int*)p;               p += SZ_RROW;
  int*    w_olst = (int*)p;               p += SZ_OLST;
  float*  w_eT   = (float*)p;             p += SZ_ET;
  int*    w_ccnt = (int*)p;               p += SZ_CCNT;
  int*    w_cand = (int*)p;               p += SZ_CAND;

  k_prep  <<<dim3(512),   dim3(256), 0, stream>>>(embed, w_senp, w_eT, w_rcnt, w_ocnt, w_ccnt);
  k_epack <<<dim3(16),    dim3(256), 0, stream>>>(embed, w_efr);
  k_xsplit<<<dim3(16384), dim3(256), 0, stream>>>(x, w_xfr, w_xT);
  k_argmin<<<dim3(1024),  dim3(512), 0, stream>>>(w_xfr, w_efr, w_senp, w_idx, w_rcnt, w_rrows, w_ccnt, w_cand);
  k_refine<<<dim3(2048),  dim3(256), 0, stream>>>(x, w_xT, embed, w_senp, w_rcnt, w_rrows, w_ccnt, w_cand, w_ocnt, w_olst, w_idx);
  k_refine_full<<<dim3(256), dim3(512), 0, stream>>>(x, w_xT, w_eT, w_senp, w_ocnt, w_olst, w_idx);
  k_gather<<<dim3(1024),  dim3(256), 0, stream>>>(x, embed, w_idx, out_q, w_lp);
  k_pplx  <<<dim3(32),    dim3(256), 0, stream>>>(w_idx, out_idxf, w_cnt);
  k_final <<<dim3(1),     dim3(256), 0, stream>>>(w_lp, w_cnt, out_loss, out_pplx);
}